// Round 1
// baseline (2227.334 us; speedup 1.0000x reference)
//
#include <hip/hip_runtime.h>

#define IN_F  32
#define HID_F 64
#define OUT_F 32

// ---------------- degree ----------------
__global__ void deg_kernel(const int* __restrict__ dst, int* __restrict__ deg, int E) {
    int e = blockIdx.x * blockDim.x + threadIdx.x;
    if (e < E) atomicAdd(&deg[dst[e]], 1);
}

__global__ void dinv_kernel(const int* __restrict__ deg, float* __restrict__ dinv, int n) {
    int i = blockIdx.x * blockDim.x + threadIdx.x;
    if (i < n) dinv[i] = rsqrtf((float)(deg[i] + 1));   // +1 self-loop; always >= 1
}

// ---------------- layer-1 matmul: hs1[i][j] = dinv[i] * sum_k x[i][k] W1[k][j] ----------------
__global__ __launch_bounds__(256) void matmul1_kernel(
    const float* __restrict__ x, const float* __restrict__ W1,
    const float* __restrict__ dinv, float* __restrict__ hs1, int n)
{
    __shared__ float Ws[IN_F * HID_F];   // 8 KB
    __shared__ float xs[4][IN_F];
    int tid = threadIdx.x;
    for (int t = tid; t < IN_F * HID_F; t += 256) Ws[t] = W1[t];
    int node0 = blockIdx.x * 4;
    if (tid < 4 * IN_F) {
        int r = tid >> 5, c = tid & 31;
        int nn = node0 + r;
        xs[r][c] = (nn < n) ? x[nn * IN_F + c] : 0.f;
    }
    __syncthreads();
    int ty = tid >> 6;        // 0..3
    int j  = tid & 63;
    int node = node0 + ty;
    if (node < n) {
        float acc = 0.f;
        #pragma unroll
        for (int k = 0; k < IN_F; ++k) acc += xs[ty][k] * Ws[k * HID_F + j];
        hs1[node * HID_F + j] = dinv[node] * acc;
    }
}

// ---------------- edge scatter, layer 1: acc1[d] += hs1[s] (64 floats, 16 thr/edge) ----------------
__global__ __launch_bounds__(256) void scatter1_kernel(
    const int* __restrict__ src, const int* __restrict__ dst,
    const float* __restrict__ hs1, float* __restrict__ acc1, int E)
{
    int t = blockIdx.x * blockDim.x + threadIdx.x;
    int e = t >> 4;
    if (e >= E) return;
    int q = (t & 15) << 2;
    int s = src[e], d = dst[e];
    float4 v = *(const float4*)(hs1 + (size_t)s * HID_F + q);
    float* p = acc1 + (size_t)d * HID_F + q;
    atomicAdd(p + 0, v.x); atomicAdd(p + 1, v.y);
    atomicAdd(p + 2, v.z); atomicAdd(p + 3, v.w);
}

// ---------------- finalize layer 1: out1 = relu(dinv*(acc1 + hs1) + b1), in-place into acc1 ----------------
__global__ void finalize1_kernel(const float* __restrict__ hs1, float* __restrict__ acc1,
                                 const float* __restrict__ dinv, const float* __restrict__ b1, int n)
{
    int t = blockIdx.x * blockDim.x + threadIdx.x;
    if (t >= n * HID_F) return;
    int i = t >> 6, j = t & 63;
    float v = dinv[i] * (acc1[t] + hs1[t]) + b1[j];
    acc1[t] = v > 0.f ? v : 0.f;
}

// ---------------- layer-2 matmul: hs2[i][j] = dinv[i] * sum_k h[i][k] W2[k][j] ----------------
__global__ __launch_bounds__(256) void matmul2_kernel(
    const float* __restrict__ h, const float* __restrict__ W2,
    const float* __restrict__ dinv, float* __restrict__ hs2, int n)
{
    __shared__ float Ws[HID_F * OUT_F];  // 8 KB
    __shared__ float xs[8][HID_F];       // 2 KB
    int tid = threadIdx.x;
    for (int t = tid; t < HID_F * OUT_F; t += 256) Ws[t] = W2[t];
    int node0 = blockIdx.x * 8;
    for (int t = tid; t < 8 * HID_F; t += 256) {
        int r = t >> 6, c = t & 63;
        int nn = node0 + r;
        xs[r][c] = (nn < n) ? h[(size_t)nn * HID_F + c] : 0.f;
    }
    __syncthreads();
    int ty = tid >> 5;        // 0..7
    int j  = tid & 31;
    int node = node0 + ty;
    if (node < n) {
        float acc = 0.f;
        #pragma unroll
        for (int k = 0; k < HID_F; ++k) acc += xs[ty][k] * Ws[k * OUT_F + j];
        hs2[(size_t)node * OUT_F + j] = dinv[node] * acc;
    }
}

// ---------------- edge scatter, layer 2: out[d] += hs2[s] (32 floats, 8 thr/edge) ----------------
__global__ __launch_bounds__(256) void scatter2_kernel(
    const int* __restrict__ src, const int* __restrict__ dst,
    const float* __restrict__ hs2, float* __restrict__ out, int E)
{
    int t = blockIdx.x * blockDim.x + threadIdx.x;
    int e = t >> 3;
    if (e >= E) return;
    int q = (t & 7) << 2;
    int s = src[e], d = dst[e];
    float4 v = *(const float4*)(hs2 + (size_t)s * OUT_F + q);
    float* p = out + (size_t)d * OUT_F + q;
    atomicAdd(p + 0, v.x); atomicAdd(p + 1, v.y);
    atomicAdd(p + 2, v.z); atomicAdd(p + 3, v.w);
}

// ---------------- finalize layer 2: out = dinv*(out + hs2) + b2 (no relu) ----------------
__global__ void finalize2_kernel(const float* __restrict__ hs2, float* __restrict__ out,
                                 const float* __restrict__ dinv, const float* __restrict__ b2, int n)
{
    int t = blockIdx.x * blockDim.x + threadIdx.x;
    if (t >= n * OUT_F) return;
    int i = t >> 5, j = t & 31;
    out[t] = dinv[i] * (out[t] + hs2[t]) + b2[j];
}

extern "C" void kernel_launch(void* const* d_in, const int* in_sizes, int n_in,
                              void* d_out, int out_size, void* d_ws, size_t ws_size,
                              hipStream_t stream) {
    const float* x  = (const float*)d_in[0];
    const int*   ei = (const int*)  d_in[1];
    const float* W1 = (const float*)d_in[2];
    const float* b1 = (const float*)d_in[3];
    const float* W2 = (const float*)d_in[4];
    const float* b2 = (const float*)d_in[5];
    float* out = (float*)d_out;

    const int n = in_sizes[0] / IN_F;     // 100000
    const int E = in_sizes[1] / 2;        // 1600000
    const int* src = ei;
    const int* dst = ei + E;

    float* ws   = (float*)d_ws;
    int*   deg  = (int*)ws;               // [n] ints
    float* dinv = ws + n;                 // [n]
    float* hs1  = dinv + n;               // [n*64]
    float* acc1 = hs1 + (size_t)n * HID_F;// [n*64]  (becomes out1 in-place)
    float* hs2  = hs1;                    // reuse hs1 region for layer 2 ([n*32])

    // zero-init accumulators (ws/d_out are poisoned 0xAA before every call)
    hipMemsetAsync(deg,  0, (size_t)n * sizeof(int), stream);
    hipMemsetAsync(acc1, 0, (size_t)n * HID_F * sizeof(float), stream);
    hipMemsetAsync(out,  0, (size_t)n * OUT_F * sizeof(float), stream);

    deg_kernel <<<(E + 255) / 256, 256, 0, stream>>>(dst, deg, E);
    dinv_kernel<<<(n + 255) / 256, 256, 0, stream>>>(deg, dinv, n);

    // layer 1
    matmul1_kernel <<<(n + 3) / 4, 256, 0, stream>>>(x, W1, dinv, hs1, n);
    scatter1_kernel<<<((size_t)E * 16 + 255) / 256, 256, 0, stream>>>(src, dst, hs1, acc1, E);
    finalize1_kernel<<<((size_t)n * HID_F + 255) / 256, 256, 0, stream>>>(hs1, acc1, dinv, b1, n);

    // layer 2 (input = acc1, i.e. relu'd layer-1 output)
    matmul2_kernel <<<(n + 7) / 8, 256, 0, stream>>>(acc1, W2, dinv, hs2, n);
    scatter2_kernel<<<((size_t)E * 8 + 255) / 256, 256, 0, stream>>>(src, dst, hs2, out, E);
    finalize2_kernel<<<((size_t)n * OUT_F + 255) / 256, 256, 0, stream>>>(hs2, out, dinv, b2, n);
}

// Round 3
// 473.064 us; speedup vs baseline: 4.7083x; 4.7083x over previous
//
#include <hip/hip_runtime.h>

#define IN_F  32
#define HID_F 64
#define OUT_F 32

// ================= degree & dinv =================
__global__ void deg_kernel(const int* __restrict__ dst, int* __restrict__ deg, int E) {
    int e = blockIdx.x * blockDim.x + threadIdx.x;
    if (e < E) atomicAdd(&deg[dst[e]], 1);
}

__global__ void dinv_kernel(const int* __restrict__ deg, float* __restrict__ dinv, int n) {
    int i = blockIdx.x * blockDim.x + threadIdx.x;
    if (i < n) dinv[i] = rsqrtf((float)(deg[i] + 1));   // +1 self-loop
}

// ================= hierarchical exclusive scan over deg -> rowstart =================
__global__ __launch_bounds__(256) void scan1_kernel(const int* __restrict__ deg,
                                                    int* __restrict__ rowstart,
                                                    int* __restrict__ partials, int n)
{
    __shared__ int s[256];
    int tid = threadIdx.x;
    int i = blockIdx.x * 256 + tid;
    int my = (i < n) ? deg[i] : 0;
    s[tid] = my;
    __syncthreads();
    for (int off = 1; off < 256; off <<= 1) {
        int v = (tid >= off) ? s[tid - off] : 0;
        __syncthreads();
        s[tid] += v;
        __syncthreads();
    }
    if (i < n) rowstart[i] = s[tid] - my;          // exclusive within block
    if (tid == 255) partials[blockIdx.x] = s[255]; // block total
}

__global__ __launch_bounds__(512) void scan2_kernel(int* __restrict__ partials, int nb)
{
    __shared__ int s[512];
    int tid = threadIdx.x;
    int my = (tid < nb) ? partials[tid] : 0;
    s[tid] = my;
    __syncthreads();
    for (int off = 1; off < 512; off <<= 1) {
        int v = (tid >= off) ? s[tid - off] : 0;
        __syncthreads();
        s[tid] += v;
        __syncthreads();
    }
    if (tid < nb) partials[tid] = s[tid] - my;     // exclusive
}

__global__ void scan3_kernel(int* __restrict__ rowstart, const int* __restrict__ partials,
                             int n, int E)
{
    int i = blockIdx.x * blockDim.x + threadIdx.x;
    if (i < n) rowstart[i] += partials[blockIdx.x];
    if (i == 0) rowstart[n] = E;
}

// ================= counting-sort fill: srcs grouped by dst =================
// destroys deg (used as a downward cursor via atomicSub) — deg is dead after scan1/dinv
__global__ void fill_kernel(const int* __restrict__ src, const int* __restrict__ dst,
                            const int* __restrict__ rowstart, int* __restrict__ deg_cursor,
                            int* __restrict__ srcs_sorted, int E)
{
    int e = blockIdx.x * blockDim.x + threadIdx.x;
    if (e < E) {
        int d = dst[e];
        int pos = rowstart[d] + atomicSub(&deg_cursor[d], 1) - 1;
        srcs_sorted[pos] = src[e];
    }
}

// ================= layer-1 matmul: hs1[i][j] = dinv[i] * (x @ W1)[i][j] =================
__global__ __launch_bounds__(256) void matmul1_kernel(
    const float* __restrict__ x, const float* __restrict__ W1,
    const float* __restrict__ dinv, float* __restrict__ hs1, int n)
{
    __shared__ float Ws[IN_F * HID_F];   // 8 KB
    __shared__ float xs[4][IN_F];
    int tid = threadIdx.x;
    for (int t = tid; t < IN_F * HID_F; t += 256) Ws[t] = W1[t];
    int node0 = blockIdx.x * 4;
    if (tid < 4 * IN_F) {
        int r = tid >> 5, c = tid & 31;
        int nn = node0 + r;
        xs[r][c] = (nn < n) ? x[nn * IN_F + c] : 0.f;
    }
    __syncthreads();
    int ty = tid >> 6;        // 0..3
    int j  = tid & 63;
    int node = node0 + ty;
    if (node < n) {
        float acc = 0.f;
        #pragma unroll
        for (int k = 0; k < IN_F; ++k) acc += xs[ty][k] * Ws[k * HID_F + j];
        hs1[(size_t)node * HID_F + j] = dinv[node] * acc;
    }
}

// ================= fused: layer-1 aggregate + relu + layer-2 matvec =================
// one wave per node. lane = feature k of h1 row. No shuffles: broadcast srcs loads,
// LDS for the 64->32 matvec. Barriers are outside all divergence.
__global__ __launch_bounds__(256) void agg1_fused_kernel(
    const int* __restrict__ rowstart, const int* __restrict__ srcs,
    const float* __restrict__ hs1, const float* __restrict__ dinv,
    const float* __restrict__ b1, const float* __restrict__ W2,
    float* __restrict__ hs2, int n)
{
    __shared__ float W2s[HID_F * OUT_F];   // 8 KB, [k*32+j]
    __shared__ float hrow[4][HID_F];       // 1 KB
    __shared__ float psum[4][OUT_F];       // 0.5 KB
    int tid = threadIdx.x;
    for (int t = tid; t < HID_F * OUT_F; t += 256) W2s[t] = W2[t];
    __syncthreads();

    int w = tid >> 6, lane = tid & 63;
    int node = blockIdx.x * 4 + w;
    bool active = node < n;
    int nodec = active ? node : 0;

    // ---- gather: acc = hs1[node] (self-loop) + sum_{s in in(node)} hs1[s] ----
    int beg = rowstart[nodec], end = active ? rowstart[nodec + 1] : beg;
    float acc = active ? hs1[(size_t)nodec * HID_F + lane] : 0.f;
    float acc_b = 0.f;
    int e = beg;
    for (; e + 2 <= end; e += 2) {
        int s0 = srcs[e], s1 = srcs[e + 1];        // broadcast within wave
        acc   += hs1[(size_t)s0 * HID_F + lane];
        acc_b += hs1[(size_t)s1 * HID_F + lane];
    }
    if (e < end) acc += hs1[(size_t)srcs[e] * HID_F + lane];
    acc += acc_b;

    float dv = dinv[nodec];
    float h = fmaxf(dv * acc + b1[lane], 0.f);     // layer-1 output feature `lane`
    hrow[w][lane] = h;
    __syncthreads();

    // ---- matvec: hs2[node][j] = dinv[node] * sum_k hrow[k] * W2[k][j] ----
    int half = lane >> 5, j = lane & 31;
    int k0 = half << 5;
    float p = 0.f;
    #pragma unroll
    for (int kk = 0; kk < 32; ++kk) {
        int k = k0 + kk;
        p += hrow[w][k] * W2s[k * OUT_F + j];
    }
    if (half == 1) psum[w][j] = p;
    __syncthreads();
    if (active && half == 0)
        hs2[(size_t)node * OUT_F + j] = dv * (p + psum[w][j]);
}

// ================= layer-2 aggregate + finalize =================
// half-wave (32 lanes) per node; broadcast srcs loads, unroll-2 dual accumulators
__global__ __launch_bounds__(256) void agg2_kernel(
    const int* __restrict__ rowstart, const int* __restrict__ srcs,
    const float* __restrict__ hs2, const float* __restrict__ dinv,
    const float* __restrict__ b2, float* __restrict__ out, int n)
{
    int t = blockIdx.x * blockDim.x + threadIdx.x;
    int node = t >> 5;
    if (node >= n) return;
    int j = t & 31;
    int beg = rowstart[node], end = rowstart[node + 1];
    float acc = hs2[(size_t)node * OUT_F + j];     // self-loop
    float acc_b = 0.f;
    int e = beg;
    for (; e + 2 <= end; e += 2) {
        int s0 = srcs[e], s1 = srcs[e + 1];
        acc   += hs2[(size_t)s0 * OUT_F + j];
        acc_b += hs2[(size_t)s1 * OUT_F + j];
    }
    if (e < end) acc += hs2[(size_t)srcs[e] * OUT_F + j];
    acc += acc_b;
    out[(size_t)node * OUT_F + j] = dinv[node] * acc + b2[j];
}

extern "C" void kernel_launch(void* const* d_in, const int* in_sizes, int n_in,
                              void* d_out, int out_size, void* d_ws, size_t ws_size,
                              hipStream_t stream) {
    const float* x  = (const float*)d_in[0];
    const int*   ei = (const int*)  d_in[1];
    const float* W1 = (const float*)d_in[2];
    const float* b1 = (const float*)d_in[3];
    const float* W2 = (const float*)d_in[4];
    const float* b2 = (const float*)d_in[5];
    float* out = (float*)d_out;

    const int n = in_sizes[0] / IN_F;     // 100000
    const int E = in_sizes[1] / 2;        // 1600000
    const int* src = ei;
    const int* dst = ei + E;

    // ---- workspace layout: 46.0 MB total ----
    int* ip = (int*)d_ws;
    int* deg       = ip;                 ip += n;       // zeroed; later used as fill cursor
    int* rowstart  = ip;                 ip += n + 1;
    int* partials  = ip;                 ip += 512;
    int* srcs_srt  = ip;                 ip += E;
    float* fp = (float*)ip;
    float* dinv = fp;                    fp += n;
    float* hs1  = fp;                    fp += (size_t)n * HID_F;   // 25.6 MB
    float* hs2  = fp;                    fp += (size_t)n * OUT_F;   // 12.8 MB

    hipMemsetAsync(deg, 0, (size_t)n * sizeof(int), stream);

    const int nb = (n + 255) / 256;   // 391 scan blocks (<=512)

    deg_kernel <<<(E + 255) / 256, 256, 0, stream>>>(dst, deg, E);
    dinv_kernel<<<nb, 256, 0, stream>>>(deg, dinv, n);
    scan1_kernel<<<nb, 256, 0, stream>>>(deg, rowstart, partials, n);
    scan2_kernel<<<1, 512, 0, stream>>>(partials, nb);
    scan3_kernel<<<nb, 256, 0, stream>>>(rowstart, partials, n, E);
    matmul1_kernel<<<(n + 3) / 4, 256, 0, stream>>>(x, W1, dinv, hs1, n);
    fill_kernel<<<(E + 255) / 256, 256, 0, stream>>>(src, dst, rowstart, deg, srcs_srt, E);

    agg1_fused_kernel<<<(n + 3) / 4, 256, 0, stream>>>(rowstart, srcs_srt, hs1, dinv, b1, W2, hs2, n);
    agg2_kernel<<<((size_t)n * 32 + 255) / 256, 256, 0, stream>>>(rowstart, srcs_srt, hs2, dinv, b2, out, n);
}

// Round 4
// 390.386 us; speedup vs baseline: 5.7055x; 1.2118x over previous
//
#include <hip/hip_runtime.h>

#define IN_F  32
#define HID_F 64
#define OUT_F 32

// ================= degree & dinv =================
__global__ void deg_kernel(const int* __restrict__ dst, int* __restrict__ deg, int E) {
    int e = blockIdx.x * blockDim.x + threadIdx.x;
    if (e < E) atomicAdd(&deg[dst[e]], 1);
}

__global__ void dinv_kernel(const int* __restrict__ deg, float* __restrict__ dinv, int n) {
    int i = blockIdx.x * blockDim.x + threadIdx.x;
    if (i < n) dinv[i] = rsqrtf((float)(deg[i] + 1));   // +1 self-loop
}

// ================= xs[i][j] = dinv[i] * x[i][j]  (float4) =================
__global__ void xs_kernel(const float* __restrict__ x, const float* __restrict__ dinv,
                          float* __restrict__ xs, int n) {
    int t = blockIdx.x * blockDim.x + threadIdx.x;
    if (t < n * (IN_F / 4)) {
        float d = dinv[t >> 3];
        float4 v = ((const float4*)x)[t];
        v.x *= d; v.y *= d; v.z *= d; v.w *= d;
        ((float4*)xs)[t] = v;
    }
}

// ================= hierarchical exclusive scan over deg -> rowstart =================
__global__ __launch_bounds__(256) void scan1_kernel(const int* __restrict__ deg,
                                                    int* __restrict__ rowstart,
                                                    int* __restrict__ partials, int n)
{
    __shared__ int s[256];
    int tid = threadIdx.x;
    int i = blockIdx.x * 256 + tid;
    int my = (i < n) ? deg[i] : 0;
    s[tid] = my;
    __syncthreads();
    for (int off = 1; off < 256; off <<= 1) {
        int v = (tid >= off) ? s[tid - off] : 0;
        __syncthreads();
        s[tid] += v;
        __syncthreads();
    }
    if (i < n) rowstart[i] = s[tid] - my;
    if (tid == 255) partials[blockIdx.x] = s[255];
}

__global__ __launch_bounds__(512) void scan2_kernel(int* __restrict__ partials, int nb)
{
    __shared__ int s[512];
    int tid = threadIdx.x;
    int my = (tid < nb) ? partials[tid] : 0;
    s[tid] = my;
    __syncthreads();
    for (int off = 1; off < 512; off <<= 1) {
        int v = (tid >= off) ? s[tid - off] : 0;
        __syncthreads();
        s[tid] += v;
        __syncthreads();
    }
    if (tid < nb) partials[tid] = s[tid] - my;
}

__global__ void scan3_kernel(int* __restrict__ rowstart, const int* __restrict__ partials,
                             int n, int E)
{
    int i = blockIdx.x * blockDim.x + threadIdx.x;
    if (i < n) rowstart[i] += partials[blockIdx.x];
    if (i == 0) rowstart[n] = E;
}

// ================= counting-sort fill (destroys deg as downward cursor) =================
__global__ void fill_kernel(const int* __restrict__ src, const int* __restrict__ dst,
                            const int* __restrict__ rowstart, int* __restrict__ deg_cursor,
                            int* __restrict__ srcs_sorted, int E)
{
    int e = blockIdx.x * blockDim.x + threadIdx.x;
    if (e < E) {
        int d = dst[e];
        int pos = rowstart[d] + atomicSub(&deg_cursor[d], 1) - 1;
        srcs_sorted[pos] = src[e];
    }
}

// ================= fused1: gather xs -> g -> W1+relu -> W2 -> hs2 =================
// 8 nodes/block, half-wave (32 lanes) per node, lane = feature j.
// g[d] = dinv[d]*(xs[d] + sum_s xs[s]);  h = relu(g@W1+b1);  hs2[d] = dinv[d]*(h@W2)
__global__ __launch_bounds__(256) void fused1_kernel(
    const int* __restrict__ rowstart, const int* __restrict__ srcs,
    const float* __restrict__ xs, const float* __restrict__ dinv,
    const float* __restrict__ b1, const float* __restrict__ W1,
    const float* __restrict__ W2, float* __restrict__ hs2, int n)
{
    __shared__ float W1s[IN_F * HID_F];    // 8 KB  [k*64+j]
    __shared__ float W2s[HID_F * OUT_F];   // 8 KB  [k*32+j]
    __shared__ float grow[8][IN_F];        // 1 KB
    __shared__ float hrow[8][HID_F];       // 2 KB
    int tid = threadIdx.x;
    for (int t = tid; t < IN_F * HID_F; t += 256) W1s[t] = W1[t];
    for (int t = tid; t < HID_F * OUT_F; t += 256) W2s[t] = W2[t];

    int sub = tid >> 5, j = tid & 31;
    int node = blockIdx.x * 8 + sub;
    bool active = node < n;
    int nodec = active ? node : 0;

    // ---- gather (quad accumulators for MLP) ----
    int beg = rowstart[nodec], end = active ? rowstart[nodec + 1] : beg;
    float a0 = active ? xs[(size_t)nodec * IN_F + j] : 0.f;   // self-loop
    float a1 = 0.f, a2 = 0.f, a3 = 0.f;
    int e = beg;
    for (; e + 4 <= end; e += 4) {
        int s0 = srcs[e], s1 = srcs[e + 1], s2 = srcs[e + 2], s3 = srcs[e + 3];
        a0 += xs[(size_t)s0 * IN_F + j];
        a1 += xs[(size_t)s1 * IN_F + j];
        a2 += xs[(size_t)s2 * IN_F + j];
        a3 += xs[(size_t)s3 * IN_F + j];
    }
    for (; e < end; ++e) a0 += xs[(size_t)srcs[e] * IN_F + j];
    float dv = dinv[nodec];
    grow[sub][j] = dv * ((a0 + a1) + (a2 + a3));
    __syncthreads();

    // ---- matvec W1 (32->64) + bias + relu; lane j computes features j and j+32 ----
    float h0 = b1[j], h1v = b1[j + 32];
    #pragma unroll
    for (int k = 0; k < IN_F; ++k) {
        float gk = grow[sub][k];
        h0  += gk * W1s[k * HID_F + j];
        h1v += gk * W1s[k * HID_F + j + 32];
    }
    hrow[sub][j]      = fmaxf(h0, 0.f);
    hrow[sub][j + 32] = fmaxf(h1v, 0.f);
    __syncthreads();

    // ---- matvec W2 (64->32), scale by dinv ----
    float p = 0.f;
    #pragma unroll
    for (int k = 0; k < HID_F; ++k) p += hrow[sub][k] * W2s[k * OUT_F + j];
    if (active) hs2[(size_t)node * OUT_F + j] = dv * p;
}

// ================= agg2: gather hs2 + self, finalize =================
__global__ __launch_bounds__(256) void agg2_kernel(
    const int* __restrict__ rowstart, const int* __restrict__ srcs,
    const float* __restrict__ hs2, const float* __restrict__ dinv,
    const float* __restrict__ b2, float* __restrict__ out, int n)
{
    int t = blockIdx.x * blockDim.x + threadIdx.x;
    int node = t >> 5;
    if (node >= n) return;
    int j = t & 31;
    int beg = rowstart[node], end = rowstart[node + 1];
    float a0 = hs2[(size_t)node * OUT_F + j];   // self-loop
    float a1 = 0.f, a2 = 0.f, a3 = 0.f;
    int e = beg;
    for (; e + 4 <= end; e += 4) {
        int s0 = srcs[e], s1 = srcs[e + 1], s2 = srcs[e + 2], s3 = srcs[e + 3];
        a0 += hs2[(size_t)s0 * OUT_F + j];
        a1 += hs2[(size_t)s1 * OUT_F + j];
        a2 += hs2[(size_t)s2 * OUT_F + j];
        a3 += hs2[(size_t)s3 * OUT_F + j];
    }
    for (; e < end; ++e) a0 += hs2[(size_t)srcs[e] * OUT_F + j];
    out[(size_t)node * OUT_F + j] = dinv[node] * ((a0 + a1) + (a2 + a3)) + b2[j];
}

extern "C" void kernel_launch(void* const* d_in, const int* in_sizes, int n_in,
                              void* d_out, int out_size, void* d_ws, size_t ws_size,
                              hipStream_t stream) {
    const float* x  = (const float*)d_in[0];
    const int*   ei = (const int*)  d_in[1];
    const float* W1 = (const float*)d_in[2];
    const float* b1 = (const float*)d_in[3];
    const float* W2 = (const float*)d_in[4];
    const float* b2 = (const float*)d_in[5];
    float* out = (float*)d_out;

    const int n = in_sizes[0] / IN_F;     // 100000
    const int E = in_sizes[1] / 2;        // 1600000
    const int* src = ei;
    const int* dst = ei + E;

    // ---- workspace layout: ~33 MB total ----
    int* ip = (int*)d_ws;
    int* deg       = ip;                 ip += n;       // zeroed; later = fill cursor
    int* rowstart  = ip;                 ip += n + 1;
    int* partials  = ip;                 ip += 512;
    int* srcs_srt  = ip;                 ip += E;
    float* fp = (float*)ip;
    float* dinv = fp;                    fp += n;
    float* xs   = fp;                    fp += (size_t)n * IN_F;    // 12.8 MB
    float* hs2  = fp;                    fp += (size_t)n * OUT_F;   // 12.8 MB

    hipMemsetAsync(deg, 0, (size_t)n * sizeof(int), stream);

    const int nb = (n + 255) / 256;   // 391 scan blocks (<=512)

    deg_kernel <<<(E + 255) / 256, 256, 0, stream>>>(dst, deg, E);
    dinv_kernel<<<nb, 256, 0, stream>>>(deg, dinv, n);
    xs_kernel  <<<((size_t)n * 8 + 255) / 256, 256, 0, stream>>>(x, dinv, xs, n);
    scan1_kernel<<<nb, 256, 0, stream>>>(deg, rowstart, partials, n);
    scan2_kernel<<<1, 512, 0, stream>>>(partials, nb);
    scan3_kernel<<<nb, 256, 0, stream>>>(rowstart, partials, n, E);
    fill_kernel<<<(E + 255) / 256, 256, 0, stream>>>(src, dst, rowstart, deg, srcs_srt, E);

    fused1_kernel<<<(n + 7) / 8, 256, 0, stream>>>(rowstart, srcs_srt, xs, dinv, b1, W1, W2, hs2, n);
    agg2_kernel<<<((size_t)n * 32 + 255) / 256, 256, 0, stream>>>(rowstart, srcs_srt, hs2, dinv, b2, out, n);
}